// Round 17
// baseline (52.027 us; speedup 1.0000x reference)
//
#include <hip/hip_runtime.h>

#define CDIM 256
#define NDET 900
#define NMAP 100
#define NPTS 20
#define NBLK (NDET + NMAP)

// ws: acc6 = [6][1000][256] floats
#define ACC6(cam, pt) (((cam) * 1000 + (pt)) * CDIM)

// ---------- K1: one (pt, cam) block; all 4 levels in ONE latency batch ----------
__global__ __launch_bounds__(256, 4) void k1_gather(
    const float* __restrict__ p2, const float* __restrict__ p3,
    const float* __restrict__ p4, const float* __restrict__ p5,
    const float* __restrict__ Kin, const float* __restrict__ Ein,
    const float* __restrict__ det3d, const float* __restrict__ mapanch,
    float* __restrict__ acc6)
{
    const int id = blockIdx.x;        // 0..5999, cam-major
    const int t  = threadIdx.x;       // channel
    const int cam = id / 1000;
    const int pt  = id % 1000;
    const bool isDet = (pt < NDET);
    const int m = pt - NDET;

    // per-thread scalar setup (uniform across block; L1-hot)
    float h0, h1, h2;
    if (isDet) {
        h0 = det3d[pt * 3 + 0];
        h1 = det3d[pt * 3 + 1];
        h2 = det3d[pt * 3 + 2];
    } else {
        float cx = 0.f, cy = 0.f;
        #pragma unroll
        for (int j = 0; j < NPTS; ++j) {
            cx += mapanch[(m * NPTS + j) * 2 + 0];
            cy += mapanch[(m * NPTS + j) * 2 + 1];
        }
        h0 = cx / (float)NPTS; h1 = cy / (float)NPTS; h2 = 0.f;
    }
    float pc[3];
    #pragma unroll
    for (int i = 0; i < 3; ++i) {
        pc[i] = Ein[cam * 16 + i * 4 + 0] * h0
              + Ein[cam * 16 + i * 4 + 1] * h1
              + Ein[cam * 16 + i * 4 + 2] * h2
              + Ein[cam * 16 + i * 4 + 3] * 1.f;
    }
    const float q0 = Kin[cam*9+0]*pc[0] + Kin[cam*9+1]*pc[1] + Kin[cam*9+2]*pc[2];
    const float q1 = Kin[cam*9+3]*pc[0] + Kin[cam*9+4]*pc[1] + Kin[cam*9+5]*pc[2];
    const float q2 = Kin[cam*9+6]*pc[0] + Kin[cam*9+7]*pc[1] + Kin[cam*9+8]*pc[2];
    const float depth = q2;
    const float u = q0 / (depth + 1e-6f);
    const float v = q1 / (depth + 1e-6f);
    const bool valid = (depth > 0.1f);
    const float gx = u / 640.0f * 2.0f - 1.0f;
    const float gy = v / 480.0f * 2.0f - 1.0f;

    float res = 0.f;
    if (valid) {                       // block-uniform
        const int Hs[4] = {120, 60, 30, 15};
        const int Ws[4] = {160, 80, 40, 20};
        const float* fp[4] = {p2, p3, p4, p5};

        int   off[4][4];
        float w[4][4];
        bool  anyl[4];
        #pragma unroll
        for (int l = 0; l < 4; ++l) {
            const int H = Hs[l], W = Ws[l];
            const float x = (gx + 1.f) * (W * 0.5f) - 0.5f;
            const float y = (gy + 1.f) * (H * 0.5f) - 0.5f;
            const float x0f = floorf(x), y0f = floorf(y);
            const float wx1 = x - x0f, wx0 = 1.f - wx1;
            const float wy1 = y - y0f, wy0 = 1.f - wy1;
            const float x1f = x0f + 1.f, y1f = y0f + 1.f;
            const bool bx0 = (x0f >= 0.f) && (x0f <= (float)(W - 1));
            const bool bx1 = (x1f >= 0.f) && (x1f <= (float)(W - 1));
            const bool by0 = (y0f >= 0.f) && (y0f <= (float)(H - 1));
            const bool by1 = (y1f >= 0.f) && (y1f <= (float)(H - 1));
            const int xc0 = (int)fminf(fmaxf(x0f, 0.f), (float)(W - 1));
            const int xc1 = (int)fminf(fmaxf(x1f, 0.f), (float)(W - 1));
            const int yc0 = (int)fminf(fmaxf(y0f, 0.f), (float)(H - 1));
            const int yc1 = (int)fminf(fmaxf(y1f, 0.f), (float)(H - 1));
            const int base = (cam * CDIM + t) * H * W;   // channel-major
            off[l][0] = base + yc0 * W + xc0;
            off[l][1] = base + yc0 * W + xc1;
            off[l][2] = base + yc1 * W + xc0;
            off[l][3] = base + yc1 * W + xc1;
            w[l][0] = (bx0 && by0) ? wx0 * wy0 : 0.f;
            w[l][1] = (bx1 && by0) ? wx1 * wy0 : 0.f;
            w[l][2] = (bx0 && by1) ? wx0 * wy1 : 0.f;
            w[l][3] = (bx1 && by1) ? wx1 * wy1 : 0.f;
            anyl[l] = (w[l][0] + w[l][1] + w[l][2] + w[l][3]) != 0.f;
        }

        // issue ALL valid levels' loads before any use -> one latency batch
        float vv[4][4];
        #pragma unroll
        for (int l = 0; l < 4; ++l) {
            if (anyl[l]) {             // block-uniform
                const float* __restrict__ f = fp[l];
                vv[l][0] = f[off[l][0]];
                vv[l][1] = f[off[l][1]];
                vv[l][2] = f[off[l][2]];
                vv[l][3] = f[off[l][3]];
            } else {
                vv[l][0] = 0.f; vv[l][1] = 0.f; vv[l][2] = 0.f; vv[l][3] = 0.f;
            }
        }
        #pragma unroll
        for (int l = 0; l < 4; ++l) {
            res += w[l][0] * vv[l][0] + w[l][1] * vv[l][1]
                 + w[l][2] * vv[l][2] + w[l][3] * vv[l][3];
        }
    }
    acc6[ACC6(cam, pt) + t] = res;
}

// ---------- K2: sum 6 camera partials + hidden GEMV + heads ----------
__global__ __launch_bounds__(256, 4) void k2_mlp_heads(
    const float* __restrict__ acc6,
    const float* __restrict__ detfull, const float* __restrict__ mapanch,
    const float* __restrict__ W1d, const float* __restrict__ b1d,
    const float* __restrict__ Wcd, const float* __restrict__ bcd,
    const float* __restrict__ Wod, const float* __restrict__ bod,
    const float* __restrict__ W1m, const float* __restrict__ b1m,
    const float* __restrict__ Wcm, const float* __restrict__ bcm,
    const float* __restrict__ Wom, const float* __restrict__ bom,
    float* __restrict__ out)
{
    const int pt = blockIdx.x;        // 0..999
    const int t  = threadIdx.x;
    const bool isDet = (pt < NDET);
    const int m = pt - NDET;

    __shared__ float s_vec[CDIM];
    __shared__ float s_hid[CDIM];

    // fixed-order sum of the 6 camera partials (deterministic)
    const float a0 = acc6[ACC6(0, pt) + t];
    const float a1 = acc6[ACC6(1, pt) + t];
    const float a2 = acc6[ACC6(2, pt) + t];
    const float a3 = acc6[ACC6(3, pt) + t];
    const float a4 = acc6[ACC6(4, pt) + t];
    const float a5 = acc6[ACC6(5, pt) + t];
    const float acc = ((((a0 + a1) + a2) + a3) + a4) + a5;
    s_vec[t] = (acc * 0.25f) / 6.0f;
    __syncthreads();

    // hidden GEMV: double-buffered 32-deep W1 batches
    const float* __restrict__ W1 = isDet ? W1d : W1m;
    const float* __restrict__ b1 = isDet ? b1d : b1m;
    float hsum = b1[t];
    const float4* sv4 = (const float4*)s_vec;
    float wvA[32], wvB[32];
    #pragma unroll
    for (int i = 0; i < 32; ++i) wvA[i] = W1[i * CDIM + t];
    #pragma unroll
    for (int k0 = 0; k0 < CDIM; k0 += 64) {
        #pragma unroll
        for (int i = 0; i < 32; ++i) wvB[i] = W1[(k0 + 32 + i) * CDIM + t];
        #pragma unroll
        for (int i = 0; i < 8; ++i) {
            const float4 x = sv4[(k0 >> 2) + i];
            hsum = fmaf(x.x, wvA[4 * i + 0], hsum);
            hsum = fmaf(x.y, wvA[4 * i + 1], hsum);
            hsum = fmaf(x.z, wvA[4 * i + 2], hsum);
            hsum = fmaf(x.w, wvA[4 * i + 3], hsum);
        }
        if (k0 + 64 < CDIM) {
            #pragma unroll
            for (int i = 0; i < 32; ++i) wvA[i] = W1[(k0 + 64 + i) * CDIM + t];
        }
        #pragma unroll
        for (int i = 0; i < 8; ++i) {
            const float4 x = sv4[(k0 >> 2) + 8 + i];
            hsum = fmaf(x.x, wvB[4 * i + 0], hsum);
            hsum = fmaf(x.y, wvB[4 * i + 1], hsum);
            hsum = fmaf(x.z, wvB[4 * i + 2], hsum);
            hsum = fmaf(x.w, wvB[4 * i + 3], hsum);
        }
    }
    s_hid[t] = fmaxf(hsum, 0.f);
    __syncthreads();

    // heads: 16 lanes per output, batched loads + shfl reduce
    const int g  = t >> 4;
    const int ln = t & 15;
    const int nOut = isDet ? 15 : 43;
    const int nrep = isDet ? 1 : 3;
    for (int rep = 0; rep < nrep; ++rep) {
        const int o = g + rep * 16;
        if (o < nOut) {
            const float* Wp; int stride, oo, ooff; float bias;
            if (isDet) {
                if (o < 4) { Wp = Wcd; stride = 4;  oo = o;     ooff = pt * 4 + oo;         bias = bcd[oo]; }
                else       { Wp = Wod; stride = 11; oo = o - 4; ooff = 3600 + pt * 11 + oo; bias = bod[oo] + detfull[pt * 11 + oo]; }
            } else {
                if (o < 3) { Wp = Wcm; stride = 3;  oo = o;     ooff = 13500 + m * 3 + oo;  bias = bcm[oo]; }
                else       { Wp = Wom; stride = 40; oo = o - 3; ooff = 13800 + m * 40 + oo; bias = bom[oo] + mapanch[m * 40 + oo]; }
            }
            float wv[16], xv[16];
            #pragma unroll
            for (int kk = 0; kk < 16; ++kk) wv[kk] = Wp[(ln + kk * 16) * stride + oo];
            #pragma unroll
            for (int kk = 0; kk < 16; ++kk) xv[kk] = s_hid[ln + kk * 16];
            float sp = 0.f;
            #pragma unroll
            for (int kk = 0; kk < 16; ++kk) sp = fmaf(xv[kk], wv[kk], sp);
            #pragma unroll
            for (int off = 1; off < 16; off <<= 1) sp += __shfl_xor(sp, off, 64);
            if (ln == 0) out[ooff] = sp + bias;
        }
    }
}

extern "C" void kernel_launch(void* const* d_in, const int* in_sizes, int n_in,
                              void* d_out, int out_size, void* d_ws, size_t ws_size,
                              hipStream_t stream) {
    const float* p2      = (const float*)d_in[0];
    const float* p3      = (const float*)d_in[1];
    const float* p4      = (const float*)d_in[2];
    const float* p5      = (const float*)d_in[3];
    const float* Kin     = (const float*)d_in[4];
    const float* Ein     = (const float*)d_in[5];
    const float* det3d   = (const float*)d_in[6];
    const float* detfull = (const float*)d_in[7];
    const float* mapanch = (const float*)d_in[8];
    const float* W1d     = (const float*)d_in[9];
    const float* b1d     = (const float*)d_in[10];
    const float* Wcd     = (const float*)d_in[11];
    const float* bcd     = (const float*)d_in[12];
    const float* Wod     = (const float*)d_in[13];
    const float* bod     = (const float*)d_in[14];
    const float* W1m     = (const float*)d_in[15];
    const float* b1m     = (const float*)d_in[16];
    const float* Wcm     = (const float*)d_in[17];
    const float* bcm     = (const float*)d_in[18];
    const float* Wom     = (const float*)d_in[19];
    const float* bom     = (const float*)d_in[20];
    float* out = (float*)d_out;
    float* acc6 = (float*)d_ws;   // [6][1000][256] floats = 6.1 MB

    k1_gather<<<6000, 256, 0, stream>>>(
        p2, p3, p4, p5, Kin, Ein, det3d, mapanch, acc6);

    k2_mlp_heads<<<NBLK, 256, 0, stream>>>(
        acc6, detfull, mapanch,
        W1d, b1d, Wcd, bcd, Wod, bod, W1m, b1m, Wcm, bcm, Wom, bom, out);
}

// Round 18
// 46.625 us; speedup vs baseline: 1.1159x; 1.1159x over previous
//
#include <hip/hip_runtime.h>

#define CDIM 256
#define NDET 900
#define NMAP 100
#define NPTS 20
#define NBLK (NDET + NMAP)

using u16 = unsigned short;

// packed bf16 layouts in ws ([cam][px][C], ushort units)
#define U4OFF 7372800    // after p3T (6*4800*256)
#define U5OFF 9216000    // after p4T (6*1200*256)
#define ACC6F 4838400    // float index after packed region; acc6: [6][1000][256] f32
#define C3STR 1228800    // 4800*256
#define C4STR 307200     // 1200*256
#define C5STR 76800      // 300*256

// K1 grid: 24 groups x (99 pack + 250 gather) = 2376 pack + 6000 gather = 8376
#define NPACK 2376
#define NGATH 6000
#define GRP   349
#define NGRPS 24

__device__ __forceinline__ u16 f2bf(float f) {
    union { float f; unsigned int i; } v; v.f = f;
    return (u16)((v.i + 0x7FFFu + ((v.i >> 16) & 1u)) >> 16);
}
__device__ __forceinline__ float bf2f(u16 u) {
    union { unsigned int i; float f; } v; v.i = ((unsigned int)u) << 16; return v.f;
}

// ---------- K1: interleaved {pack p3/p4/p5 coalesced-transpose} + {p2 gather} ----------
__global__ __launch_bounds__(256, 4) void k1_pack_p2(
    const float* __restrict__ p2, const float* __restrict__ p3,
    const float* __restrict__ p4, const float* __restrict__ p5,
    const float* __restrict__ Kin, const float* __restrict__ Ein,
    const float* __restrict__ det3d, const float* __restrict__ mapanch,
    u16* __restrict__ wsb, float* __restrict__ acc6)
{
    const int b = blockIdx.x;
    const int t = threadIdx.x;

    __shared__ float s_tile[64][65];

    const int grp = b / GRP, r = b % GRP;
    const bool isPack = (r < 99);
    if (isPack) {
        const int pid = grp * 99 + r;          // 0..2375
        const int lane = t & 63, wv = t >> 6;
        if (pid < 1800) {
            // ---- p3: 64px x 64ch transpose tile (exact) ----
            const int cam = pid / 300;
            const int rem = pid % 300;
            const int pxT = rem >> 2, chT = rem & 3;
            #pragma unroll
            for (int cc = 0; cc < 16; ++cc) {
                const int chl = wv * 16 + cc;
                s_tile[chl][lane] = p3[(cam * CDIM + chT * 64 + chl) * 4800 + pxT * 64 + lane];
            }
            __syncthreads();
            #pragma unroll
            for (int pp = 0; pp < 16; ++pp) {
                const int pxl = wv * 16 + pp;
                wsb[(cam * 4800 + pxT * 64 + pxl) * CDIM + chT * 64 + lane] = f2bf(s_tile[lane][pxl]);
            }
        } else if (pid < 2256) {
            // ---- p4: 64px x 64ch transpose tile, ragged at px=1200 ----
            const int id = pid - 1800;          // 0..455
            const int cam = id / 76;
            const int rem = id % 76;
            const int pxT = rem >> 2, chT = rem & 3;
            const int px0 = pxT * 64;
            #pragma unroll
            for (int cc = 0; cc < 16; ++cc) {
                const int chl = wv * 16 + cc;
                const int px = px0 + lane;
                s_tile[chl][lane] = (px < 1200)
                    ? p4[(cam * CDIM + chT * 64 + chl) * 1200 + px] : 0.f;
            }
            __syncthreads();
            #pragma unroll
            for (int pp = 0; pp < 16; ++pp) {
                const int pxl = wv * 16 + pp;
                const int px = px0 + pxl;
                if (px < 1200)
                    wsb[U4OFF + (cam * 1200 + px) * CDIM + chT * 64 + lane] = f2bf(s_tile[lane][pxl]);
            }
        } else {
            // ---- p5: 64px x 64ch transpose tile, ragged at px=300 ----
            const int id = pid - 2256;          // 0..119
            const int cam = id / 20;
            const int rem = id % 20;
            const int pxT = rem >> 2, chT = rem & 3;
            const int px0 = pxT * 64;
            #pragma unroll
            for (int cc = 0; cc < 16; ++cc) {
                const int chl = wv * 16 + cc;
                const int px = px0 + lane;
                s_tile[chl][lane] = (px < 300)
                    ? p5[(cam * CDIM + chT * 64 + chl) * 300 + px] : 0.f;
            }
            __syncthreads();
            #pragma unroll
            for (int pp = 0; pp < 16; ++pp) {
                const int pxl = wv * 16 + pp;
                const int px = px0 + pxl;
                if (px < 300)
                    wsb[U5OFF + (cam * 300 + px) * CDIM + chT * 64 + lane] = f2bf(s_tile[lane][pxl]);
            }
        }
        return;
    }

    // ---- level-0 (p2) gather: one (pt, cam) tile per block, one latency batch ----
    const int gid = grp * 250 + (r - 99);       // 0..5999
    const int cam = gid / 1000;
    const int pt  = gid % 1000;
    const bool isDet = (pt < NDET);
    const int m = pt - NDET;

    float h0, h1, h2;
    if (isDet) {
        h0 = det3d[pt * 3 + 0];
        h1 = det3d[pt * 3 + 1];
        h2 = det3d[pt * 3 + 2];
    } else {
        float cx = 0.f, cy = 0.f;
        #pragma unroll
        for (int j = 0; j < NPTS; ++j) {
            cx += mapanch[(m * NPTS + j) * 2 + 0];
            cy += mapanch[(m * NPTS + j) * 2 + 1];
        }
        h0 = cx / (float)NPTS; h1 = cy / (float)NPTS; h2 = 0.f;
    }
    float pc[3];
    #pragma unroll
    for (int i = 0; i < 3; ++i) {
        pc[i] = Ein[cam * 16 + i * 4 + 0] * h0
              + Ein[cam * 16 + i * 4 + 1] * h1
              + Ein[cam * 16 + i * 4 + 2] * h2
              + Ein[cam * 16 + i * 4 + 3] * 1.f;
    }
    const float q0 = Kin[cam*9+0]*pc[0] + Kin[cam*9+1]*pc[1] + Kin[cam*9+2]*pc[2];
    const float q1 = Kin[cam*9+3]*pc[0] + Kin[cam*9+4]*pc[1] + Kin[cam*9+5]*pc[2];
    const float q2 = Kin[cam*9+6]*pc[0] + Kin[cam*9+7]*pc[1] + Kin[cam*9+8]*pc[2];
    const float depth = q2;
    const float u = q0 / (depth + 1e-6f);
    const float v = q1 / (depth + 1e-6f);
    const bool valid = (depth > 0.1f);
    const float gx = u / 640.0f * 2.0f - 1.0f;
    const float gy = v / 480.0f * 2.0f - 1.0f;
    const int H = 120, W = 160;
    const float x = (gx + 1.f) * (W * 0.5f) - 0.5f;
    const float y = (gy + 1.f) * (H * 0.5f) - 0.5f;
    const float x0f = floorf(x), y0f = floorf(y);
    const float wx1 = x - x0f, wx0 = 1.f - wx1;
    const float wy1 = y - y0f, wy0 = 1.f - wy1;
    const float x1f = x0f + 1.f, y1f = y0f + 1.f;
    const bool bx0 = (x0f >= 0.f) && (x0f <= (float)(W - 1));
    const bool bx1 = (x1f >= 0.f) && (x1f <= (float)(W - 1));
    const bool by0 = (y0f >= 0.f) && (y0f <= (float)(H - 1));
    const bool by1 = (y1f >= 0.f) && (y1f <= (float)(H - 1));
    const int xc0 = (int)fminf(fmaxf(x0f, 0.f), (float)(W - 1));
    const int xc1 = (int)fminf(fmaxf(x1f, 0.f), (float)(W - 1));
    const int yc0 = (int)fminf(fmaxf(y0f, 0.f), (float)(H - 1));
    const int yc1 = (int)fminf(fmaxf(y1f, 0.f), (float)(H - 1));
    const float w0 = (bx0 && by0) ? wx0 * wy0 : 0.f;
    const float w1 = (bx1 && by0) ? wx1 * wy0 : 0.f;
    const float w2 = (bx0 && by1) ? wx0 * wy1 : 0.f;
    const float w3 = (bx1 && by1) ? wx1 * wy1 : 0.f;

    float res = 0.f;
    if (valid && ((w0 + w1 + w2 + w3) != 0.f)) {   // block-uniform
        const int base = (cam * CDIM + t) * (H * W);
        const float v0 = p2[base + yc0 * W + xc0];
        const float v1 = p2[base + yc0 * W + xc1];
        const float v2 = p2[base + yc1 * W + xc0];
        const float v3 = p2[base + yc1 * W + xc1];
        res = w0 * v0 + w1 * v1 + w2 * v2 + w3 * v3;
    }
    acc6[(cam * 1000 + pt) * CDIM + t] = res;
}

// ---------- K2: sum acc6 + levels 1-3 coalesced bf16 gather + MLP + heads ----------
__global__ __launch_bounds__(256, 4) void k2_gather_mlp(
    const u16* __restrict__ wsb, const float* __restrict__ acc6,
    const float* __restrict__ Kin, const float* __restrict__ Ein,
    const float* __restrict__ det3d, const float* __restrict__ detfull,
    const float* __restrict__ mapanch,
    const float* __restrict__ W1d, const float* __restrict__ b1d,
    const float* __restrict__ Wcd, const float* __restrict__ bcd,
    const float* __restrict__ Wod, const float* __restrict__ bod,
    const float* __restrict__ W1m, const float* __restrict__ b1m,
    const float* __restrict__ Wcm, const float* __restrict__ bcm,
    const float* __restrict__ Wom, const float* __restrict__ bom,
    float* __restrict__ out)
{
    const int pt = blockIdx.x;
    const int t  = threadIdx.x;
    const bool isDet = (pt < NDET);
    const int m = pt - NDET;

    __shared__ int   s_off[19][4];
    __shared__ float s_w[19][4];
    __shared__ int   s_list[24];
    __shared__ int   s_n;
    __shared__ float s_vec[CDIM];
    __shared__ float s_hid[CDIM];

    // level-0 partial: fixed-order sum of the 6 camera partials (deterministic)
    const float a0 = acc6[(0 * 1000 + pt) * CDIM + t];
    const float a1 = acc6[(1 * 1000 + pt) * CDIM + t];
    const float a2 = acc6[(2 * 1000 + pt) * CDIM + t];
    const float a3 = acc6[(3 * 1000 + pt) * CDIM + t];
    const float a4 = acc6[(4 * 1000 + pt) * CDIM + t];
    const float a5 = acc6[(5 * 1000 + pt) * CDIM + t];
    float acc = ((((a0 + a1) + a2) + a3) + a4) + a5;

    if (t < 19) {
        float h0, h1, h2;
        if (isDet) {
            h0 = det3d[pt * 3 + 0];
            h1 = det3d[pt * 3 + 1];
            h2 = det3d[pt * 3 + 2];
        } else {
            float cx = 0.f, cy = 0.f;
            #pragma unroll
            for (int j = 0; j < NPTS; ++j) {
                cx += mapanch[(m * NPTS + j) * 2 + 0];
                cy += mapanch[(m * NPTS + j) * 2 + 1];
            }
            h0 = cx / (float)NPTS; h1 = cy / (float)NPTS; h2 = 0.f;
        }
        bool pred = false;
        if (t < 18) {
            const int cam = t / 3, l = 1 + (t % 3);
            float pc[3];
            #pragma unroll
            for (int i = 0; i < 3; ++i) {
                pc[i] = Ein[cam * 16 + i * 4 + 0] * h0
                      + Ein[cam * 16 + i * 4 + 1] * h1
                      + Ein[cam * 16 + i * 4 + 2] * h2
                      + Ein[cam * 16 + i * 4 + 3] * 1.f;
            }
            const float q0 = Kin[cam*9+0]*pc[0] + Kin[cam*9+1]*pc[1] + Kin[cam*9+2]*pc[2];
            const float q1 = Kin[cam*9+3]*pc[0] + Kin[cam*9+4]*pc[1] + Kin[cam*9+5]*pc[2];
            const float q2 = Kin[cam*9+6]*pc[0] + Kin[cam*9+7]*pc[1] + Kin[cam*9+8]*pc[2];
            const float depth = q2;
            const float u = q0 / (depth + 1e-6f);
            const float v = q1 / (depth + 1e-6f);
            const bool valid = (depth > 0.1f);
            const float gx = u / 640.0f * 2.0f - 1.0f;
            const float gy = v / 480.0f * 2.0f - 1.0f;
            const int Hs[4] = {120, 60, 30, 15};
            const int Ws[4] = {160, 80, 40, 20};
            const int H = Hs[l], W = Ws[l];
            const float x = (gx + 1.f) * (W * 0.5f) - 0.5f;
            const float y = (gy + 1.f) * (H * 0.5f) - 0.5f;
            const float x0f = floorf(x), y0f = floorf(y);
            const float wx1 = x - x0f, wx0 = 1.f - wx1;
            const float wy1 = y - y0f, wy0 = 1.f - wy1;
            const float x1f = x0f + 1.f, y1f = y0f + 1.f;
            const bool bx0 = (x0f >= 0.f) && (x0f <= (float)(W - 1));
            const bool bx1 = (x1f >= 0.f) && (x1f <= (float)(W - 1));
            const bool by0 = (y0f >= 0.f) && (y0f <= (float)(H - 1));
            const bool by1 = (y1f >= 0.f) && (y1f <= (float)(H - 1));
            const int xc0 = (int)fminf(fmaxf(x0f, 0.f), (float)(W - 1));
            const int xc1 = (int)fminf(fmaxf(x1f, 0.f), (float)(W - 1));
            const int yc0 = (int)fminf(fmaxf(y0f, 0.f), (float)(H - 1));
            const int yc1 = (int)fminf(fmaxf(y1f, 0.f), (float)(H - 1));
            const int pb = (l == 1) ? cam * C3STR
                         : (l == 2) ? (U4OFF + cam * C4STR)
                                    : (U5OFF + cam * C5STR);
            s_off[t][0] = pb + (yc0 * W + xc0) * CDIM;
            s_off[t][1] = pb + (yc0 * W + xc1) * CDIM;
            s_off[t][2] = pb + (yc1 * W + xc0) * CDIM;
            s_off[t][3] = pb + (yc1 * W + xc1) * CDIM;
            const float w0 = (bx0 && by0) ? wx0 * wy0 : 0.f;
            const float w1 = (bx1 && by0) ? wx1 * wy0 : 0.f;
            const float w2 = (bx0 && by1) ? wx0 * wy1 : 0.f;
            const float w3 = (bx1 && by1) ? wx1 * wy1 : 0.f;
            s_w[t][0] = w0; s_w[t][1] = w1; s_w[t][2] = w2; s_w[t][3] = w3;
            pred = valid && ((w0 + w1 + w2 + w3) != 0.f);
        } else {
            s_off[18][0] = 0; s_off[18][1] = 0; s_off[18][2] = 0; s_off[18][3] = 0;
            s_w[18][0] = 0.f; s_w[18][1] = 0.f; s_w[18][2] = 0.f; s_w[18][3] = 0.f;
        }
        const unsigned long long mask = __ballot(pred);
        const int n = __popcll(mask);
        const int rank = __popcll(mask & ((1ull << t) - 1ull));
        if (pred) s_list[rank] = t;
        const int npad = (n + 7) & ~7;
        if (t < 8 && (n + t) < npad) s_list[n + t] = 18;
        if (t == 0) s_n = npad;
    }
    __syncthreads();

    const int npad = s_n;
    for (int base = 0; base < npad; base += 8) {
        float v[8][4];
        int tj[8];
        #pragma unroll
        for (int j = 0; j < 8; ++j) {
            const int tt = s_list[base + j];
            tj[j] = tt;
            v[j][0] = bf2f(wsb[s_off[tt][0] + t]);
            v[j][1] = bf2f(wsb[s_off[tt][1] + t]);
            v[j][2] = bf2f(wsb[s_off[tt][2] + t]);
            v[j][3] = bf2f(wsb[s_off[tt][3] + t]);
        }
        #pragma unroll
        for (int j = 0; j < 8; ++j) {
            const int tt = tj[j];
            acc += s_w[tt][0] * v[j][0] + s_w[tt][1] * v[j][1]
                 + s_w[tt][2] * v[j][2] + s_w[tt][3] * v[j][3];
        }
    }
    const float agg = (acc * 0.25f) / 6.0f;

    s_vec[t] = agg;
    __syncthreads();

    const float* __restrict__ W1 = isDet ? W1d : W1m;
    const float* __restrict__ b1 = isDet ? b1d : b1m;
    float hsum = b1[t];
    const float4* sv4 = (const float4*)s_vec;
    float wvA[32], wvB[32];
    #pragma unroll
    for (int i = 0; i < 32; ++i) wvA[i] = W1[i * CDIM + t];
    #pragma unroll
    for (int k0 = 0; k0 < CDIM; k0 += 64) {
        #pragma unroll
        for (int i = 0; i < 32; ++i) wvB[i] = W1[(k0 + 32 + i) * CDIM + t];
        #pragma unroll
        for (int i = 0; i < 8; ++i) {
            const float4 x = sv4[(k0 >> 2) + i];
            hsum = fmaf(x.x, wvA[4 * i + 0], hsum);
            hsum = fmaf(x.y, wvA[4 * i + 1], hsum);
            hsum = fmaf(x.z, wvA[4 * i + 2], hsum);
            hsum = fmaf(x.w, wvA[4 * i + 3], hsum);
        }
        if (k0 + 64 < CDIM) {
            #pragma unroll
            for (int i = 0; i < 32; ++i) wvA[i] = W1[(k0 + 64 + i) * CDIM + t];
        }
        #pragma unroll
        for (int i = 0; i < 8; ++i) {
            const float4 x = sv4[(k0 >> 2) + 8 + i];
            hsum = fmaf(x.x, wvB[4 * i + 0], hsum);
            hsum = fmaf(x.y, wvB[4 * i + 1], hsum);
            hsum = fmaf(x.z, wvB[4 * i + 2], hsum);
            hsum = fmaf(x.w, wvB[4 * i + 3], hsum);
        }
    }
    s_hid[t] = fmaxf(hsum, 0.f);
    __syncthreads();

    const int g  = t >> 4;
    const int ln = t & 15;
    const int nOut = isDet ? 15 : 43;
    const int nrep = isDet ? 1 : 3;
    for (int rep = 0; rep < nrep; ++rep) {
        const int o = g + rep * 16;
        if (o < nOut) {
            const float* Wp; int stride, oo, ooff; float bias;
            if (isDet) {
                if (o < 4) { Wp = Wcd; stride = 4;  oo = o;     ooff = pt * 4 + oo;         bias = bcd[oo]; }
                else       { Wp = Wod; stride = 11; oo = o - 4; ooff = 3600 + pt * 11 + oo; bias = bod[oo] + detfull[pt * 11 + oo]; }
            } else {
                if (o < 3) { Wp = Wcm; stride = 3;  oo = o;     ooff = 13500 + m * 3 + oo;  bias = bcm[oo]; }
                else       { Wp = Wom; stride = 40; oo = o - 3; ooff = 13800 + m * 40 + oo; bias = bom[oo] + mapanch[m * 40 + oo]; }
            }
            float wv[16], xv[16];
            #pragma unroll
            for (int kk = 0; kk < 16; ++kk) wv[kk] = Wp[(ln + kk * 16) * stride + oo];
            #pragma unroll
            for (int kk = 0; kk < 16; ++kk) xv[kk] = s_hid[ln + kk * 16];
            float sp = 0.f;
            #pragma unroll
            for (int kk = 0; kk < 16; ++kk) sp = fmaf(xv[kk], wv[kk], sp);
            #pragma unroll
            for (int off = 1; off < 16; off <<= 1) sp += __shfl_xor(sp, off, 64);
            if (ln == 0) out[ooff] = sp + bias;
        }
    }
}

extern "C" void kernel_launch(void* const* d_in, const int* in_sizes, int n_in,
                              void* d_out, int out_size, void* d_ws, size_t ws_size,
                              hipStream_t stream) {
    const float* p2      = (const float*)d_in[0];
    const float* p3      = (const float*)d_in[1];
    const float* p4      = (const float*)d_in[2];
    const float* p5      = (const float*)d_in[3];
    const float* Kin     = (const float*)d_in[4];
    const float* Ein     = (const float*)d_in[5];
    const float* det3d   = (const float*)d_in[6];
    const float* detfull = (const float*)d_in[7];
    const float* mapanch = (const float*)d_in[8];
    const float* W1d     = (const float*)d_in[9];
    const float* b1d     = (const float*)d_in[10];
    const float* Wcd     = (const float*)d_in[11];
    const float* bcd     = (const float*)d_in[12];
    const float* Wod     = (const float*)d_in[13];
    const float* bod     = (const float*)d_in[14];
    const float* W1m     = (const float*)d_in[15];
    const float* b1m     = (const float*)d_in[16];
    const float* Wcm     = (const float*)d_in[17];
    const float* bcm     = (const float*)d_in[18];
    const float* Wom     = (const float*)d_in[19];
    const float* bom     = (const float*)d_in[20];
    float* out = (float*)d_out;
    u16* wsb = (u16*)d_ws;                     // packed bf16 features
    float* acc6 = (float*)d_ws + ACC6F;        // [6][1000][256] level-0 partials

    k1_pack_p2<<<NPACK + NGATH, 256, 0, stream>>>(
        p2, p3, p4, p5, Kin, Ein, det3d, mapanch, wsb, acc6);

    k2_gather_mlp<<<NBLK, 256, 0, stream>>>(
        wsb, acc6, Kin, Ein, det3d, detfull, mapanch,
        W1d, b1d, Wcd, bcd, Wod, bod, W1m, b1m, Wcm, bcm, Wom, bom, out);
}

// Round 19
// 43.106 us; speedup vs baseline: 1.2070x; 1.0816x over previous
//
#include <hip/hip_runtime.h>

#define CDIM 256
#define NDET 900
#define NMAP 100
#define NPTS 20

using u16 = unsigned short;

// packed bf16 layouts in ws ([cam][px][C], ushort units)
#define U4OFF 7372800    // after p3T (6*4800*256)
#define U5OFF 9216000    // after p4T (6*1200*256)
#define UEND  9292800    // after p5T (6*300*256)
#define C3STR 1228800    // 4800*256
#define C4STR 307200     // 1200*256
#define C5STR 76800      // 300*256
// accb (bf16): [6][1000][256] ushorts starting at UEND

__device__ __forceinline__ u16 f2bf(float f) {
    union { float f; unsigned int i; } v; v.f = f;
    return (u16)((v.i + 0x7FFFu + ((v.i >> 16) & 1u)) >> 16);
}
__device__ __forceinline__ float bf2f(u16 u) {
    union { unsigned int i; float f; } v; v.i = ((unsigned int)u) << 16; return v.f;
}

// ---------- K1: pack p3 (transpose) / p4 / p5 (rows) + 6000-way p2 gather ----------
__global__ __launch_bounds__(256, 4) void k1_pack_p2(
    const float* __restrict__ p2, const float* __restrict__ p3,
    const float* __restrict__ p4, const float* __restrict__ p5,
    const float* __restrict__ Kin, const float* __restrict__ Ein,
    const float* __restrict__ det3d, const float* __restrict__ mapanch,
    u16* __restrict__ wsb, u16* __restrict__ accb)
{
    const int b = blockIdx.x;
    const int t = threadIdx.x;

    __shared__ float s_tile[64][65];

    if (b < 1800) {
        // ---- p3 transpose tile: 64 px x 64 ch, coalesced read AND write ----
        const int cam = b / 300;
        const int rem = b % 300;
        const int pxT = rem >> 2, chT = rem & 3;
        const int lane = t & 63, wv = t >> 6;
        #pragma unroll
        for (int cc = 0; cc < 16; ++cc) {
            const int chl = wv * 16 + cc;
            s_tile[chl][lane] = p3[(cam * CDIM + chT * 64 + chl) * 4800 + pxT * 64 + lane];
        }
        __syncthreads();
        #pragma unroll
        for (int pp = 0; pp < 16; ++pp) {
            const int pxl = wv * 16 + pp;
            wsb[(cam * 4800 + pxT * 64 + pxl) * CDIM + chT * 64 + lane] = f2bf(s_tile[lane][pxl]);
        }
        return;
    }
    if (b < 1980) {
        const int id = b - 1800;
        const int cam = id / 30, h = id % 30;
        const float4* __restrict__ src = (const float4*)(p4 + ((cam * CDIM + t) * 30 + h) * 40);
        u16* __restrict__ dst = wsb + U4OFF + ((cam * 30 + h) * 40) * CDIM + t;
        #pragma unroll
        for (int w4 = 0; w4 < 10; ++w4) {
            const float4 v = src[w4];
            dst[(w4 * 4 + 0) * CDIM] = f2bf(v.x);
            dst[(w4 * 4 + 1) * CDIM] = f2bf(v.y);
            dst[(w4 * 4 + 2) * CDIM] = f2bf(v.z);
            dst[(w4 * 4 + 3) * CDIM] = f2bf(v.w);
        }
        return;
    }
    if (b < 2070) {
        const int id = b - 1980;
        const int cam = id / 15, h = id % 15;
        const float4* __restrict__ src = (const float4*)(p5 + ((cam * CDIM + t) * 15 + h) * 20);
        u16* __restrict__ dst = wsb + U5OFF + ((cam * 15 + h) * 20) * CDIM + t;
        #pragma unroll
        for (int w4 = 0; w4 < 5; ++w4) {
            const float4 v = src[w4];
            dst[(w4 * 4 + 0) * CDIM] = f2bf(v.x);
            dst[(w4 * 4 + 1) * CDIM] = f2bf(v.y);
            dst[(w4 * 4 + 2) * CDIM] = f2bf(v.z);
            dst[(w4 * 4 + 3) * CDIM] = f2bf(v.w);
        }
        return;
    }

    // ---- level-0 (p2) gather: one (pt, cam) tile per block, one latency batch ----
    const int id = b - 2070;          // 0..5999, cam-major
    const int cam = id / 1000;
    const int pt = id % 1000;
    const bool isDet = (pt < NDET);
    const int m = pt - NDET;

    float h0, h1, h2;
    if (isDet) {
        h0 = det3d[pt * 3 + 0];
        h1 = det3d[pt * 3 + 1];
        h2 = det3d[pt * 3 + 2];
    } else {
        float cx = 0.f, cy = 0.f;
        #pragma unroll
        for (int j = 0; j < NPTS; ++j) {
            cx += mapanch[(m * NPTS + j) * 2 + 0];
            cy += mapanch[(m * NPTS + j) * 2 + 1];
        }
        h0 = cx / (float)NPTS; h1 = cy / (float)NPTS; h2 = 0.f;
    }
    float pc[3];
    #pragma unroll
    for (int i = 0; i < 3; ++i) {
        pc[i] = Ein[cam * 16 + i * 4 + 0] * h0
              + Ein[cam * 16 + i * 4 + 1] * h1
              + Ein[cam * 16 + i * 4 + 2] * h2
              + Ein[cam * 16 + i * 4 + 3] * 1.f;
    }
    const float q0 = Kin[cam*9+0]*pc[0] + Kin[cam*9+1]*pc[1] + Kin[cam*9+2]*pc[2];
    const float q1 = Kin[cam*9+3]*pc[0] + Kin[cam*9+4]*pc[1] + Kin[cam*9+5]*pc[2];
    const float q2 = Kin[cam*9+6]*pc[0] + Kin[cam*9+7]*pc[1] + Kin[cam*9+8]*pc[2];
    const float depth = q2;
    const float u = q0 / (depth + 1e-6f);
    const float v = q1 / (depth + 1e-6f);
    const bool valid = (depth > 0.1f);
    const float gx = u / 640.0f * 2.0f - 1.0f;
    const float gy = v / 480.0f * 2.0f - 1.0f;
    const int H = 120, W = 160;
    const float x = (gx + 1.f) * (W * 0.5f) - 0.5f;
    const float y = (gy + 1.f) * (H * 0.5f) - 0.5f;
    const float x0f = floorf(x), y0f = floorf(y);
    const float wx1 = x - x0f, wx0 = 1.f - wx1;
    const float wy1 = y - y0f, wy0 = 1.f - wy1;
    const float x1f = x0f + 1.f, y1f = y0f + 1.f;
    const bool bx0 = (x0f >= 0.f) && (x0f <= (float)(W - 1));
    const bool bx1 = (x1f >= 0.f) && (x1f <= (float)(W - 1));
    const bool by0 = (y0f >= 0.f) && (y0f <= (float)(H - 1));
    const bool by1 = (y1f >= 0.f) && (y1f <= (float)(H - 1));
    const int xc0 = (int)fminf(fmaxf(x0f, 0.f), (float)(W - 1));
    const int xc1 = (int)fminf(fmaxf(x1f, 0.f), (float)(W - 1));
    const int yc0 = (int)fminf(fmaxf(y0f, 0.f), (float)(H - 1));
    const int yc1 = (int)fminf(fmaxf(y1f, 0.f), (float)(H - 1));
    const float w0 = (bx0 && by0) ? wx0 * wy0 : 0.f;
    const float w1 = (bx1 && by0) ? wx1 * wy0 : 0.f;
    const float w2 = (bx0 && by1) ? wx0 * wy1 : 0.f;
    const float w3 = (bx1 && by1) ? wx1 * wy1 : 0.f;

    float res = 0.f;
    if (valid && ((w0 + w1 + w2 + w3) != 0.f)) {   // block-uniform
        const int base = (cam * CDIM + t) * (H * W);
        const float v0 = p2[base + yc0 * W + xc0];
        const float v1 = p2[base + yc0 * W + xc1];
        const float v2 = p2[base + yc1 * W + xc0];
        const float v3 = p2[base + yc1 * W + xc1];
        res = w0 * v0 + w1 * v1 + w2 * v2 + w3 * v3;
    }
    accb[(cam * 1000 + pt) * CDIM + t] = f2bf(res);
}

// ---------- K2: 2 points/block: partial sum + lvl1-3 gather + GEMV + heads ----------
__global__ __launch_bounds__(256, 4) void k2_gather_mlp(
    const u16* __restrict__ wsb, const u16* __restrict__ accb,
    const float* __restrict__ Kin, const float* __restrict__ Ein,
    const float* __restrict__ det3d, const float* __restrict__ detfull,
    const float* __restrict__ mapanch,
    const float* __restrict__ W1d, const float* __restrict__ b1d,
    const float* __restrict__ Wcd, const float* __restrict__ bcd,
    const float* __restrict__ Wod, const float* __restrict__ bod,
    const float* __restrict__ W1m, const float* __restrict__ b1m,
    const float* __restrict__ Wcm, const float* __restrict__ bcm,
    const float* __restrict__ Wom, const float* __restrict__ bom,
    float* __restrict__ out)
{
    const int b = blockIdx.x;       // 0..449 det pairs, 450..499 map pairs
    const int t = threadIdx.x;
    const bool isDet = (b < 450);
    const int pt0 = isDet ? (b * 2) : (NDET + (b - 450) * 2);

    __shared__ int   s_off[2][19][4];
    __shared__ float s_w[2][19][4];
    __shared__ int   s_list[2][24];
    __shared__ int   s_n[2];
    __shared__ float s_vec[2][CDIM];
    __shared__ float s_hid[2][CDIM];

    // ---- per-point setup (run twice on wave 0; cheap scalar work) ----
    #pragma unroll
    for (int p = 0; p < 2; ++p) {
        const int pt = pt0 + p;
        const int m = pt - NDET;
        if (t < 19) {
            float h0, h1, h2;
            if (isDet) {
                h0 = det3d[pt * 3 + 0];
                h1 = det3d[pt * 3 + 1];
                h2 = det3d[pt * 3 + 2];
            } else {
                float cx = 0.f, cy = 0.f;
                #pragma unroll
                for (int j = 0; j < NPTS; ++j) {
                    cx += mapanch[(m * NPTS + j) * 2 + 0];
                    cy += mapanch[(m * NPTS + j) * 2 + 1];
                }
                h0 = cx / (float)NPTS; h1 = cy / (float)NPTS; h2 = 0.f;
            }
            bool pred = false;
            if (t < 18) {
                const int cam = t / 3, l = 1 + (t % 3);
                float pc[3];
                #pragma unroll
                for (int i = 0; i < 3; ++i) {
                    pc[i] = Ein[cam * 16 + i * 4 + 0] * h0
                          + Ein[cam * 16 + i * 4 + 1] * h1
                          + Ein[cam * 16 + i * 4 + 2] * h2
                          + Ein[cam * 16 + i * 4 + 3] * 1.f;
                }
                const float q0 = Kin[cam*9+0]*pc[0] + Kin[cam*9+1]*pc[1] + Kin[cam*9+2]*pc[2];
                const float q1 = Kin[cam*9+3]*pc[0] + Kin[cam*9+4]*pc[1] + Kin[cam*9+5]*pc[2];
                const float q2 = Kin[cam*9+6]*pc[0] + Kin[cam*9+7]*pc[1] + Kin[cam*9+8]*pc[2];
                const float depth = q2;
                const float u = q0 / (depth + 1e-6f);
                const float v = q1 / (depth + 1e-6f);
                const bool valid = (depth > 0.1f);
                const float gx = u / 640.0f * 2.0f - 1.0f;
                const float gy = v / 480.0f * 2.0f - 1.0f;
                const int Hs[4] = {120, 60, 30, 15};
                const int Ws[4] = {160, 80, 40, 20};
                const int H = Hs[l], W = Ws[l];
                const float x = (gx + 1.f) * (W * 0.5f) - 0.5f;
                const float y = (gy + 1.f) * (H * 0.5f) - 0.5f;
                const float x0f = floorf(x), y0f = floorf(y);
                const float wx1 = x - x0f, wx0 = 1.f - wx1;
                const float wy1 = y - y0f, wy0 = 1.f - wy1;
                const float x1f = x0f + 1.f, y1f = y0f + 1.f;
                const bool bx0 = (x0f >= 0.f) && (x0f <= (float)(W - 1));
                const bool bx1 = (x1f >= 0.f) && (x1f <= (float)(W - 1));
                const bool by0 = (y0f >= 0.f) && (y0f <= (float)(H - 1));
                const bool by1 = (y1f >= 0.f) && (y1f <= (float)(H - 1));
                const int xc0 = (int)fminf(fmaxf(x0f, 0.f), (float)(W - 1));
                const int xc1 = (int)fminf(fmaxf(x1f, 0.f), (float)(W - 1));
                const int yc0 = (int)fminf(fmaxf(y0f, 0.f), (float)(H - 1));
                const int yc1 = (int)fminf(fmaxf(y1f, 0.f), (float)(H - 1));
                const int pb = (l == 1) ? cam * C3STR
                             : (l == 2) ? (U4OFF + cam * C4STR)
                                        : (U5OFF + cam * C5STR);
                s_off[p][t][0] = pb + (yc0 * W + xc0) * CDIM;
                s_off[p][t][1] = pb + (yc0 * W + xc1) * CDIM;
                s_off[p][t][2] = pb + (yc1 * W + xc0) * CDIM;
                s_off[p][t][3] = pb + (yc1 * W + xc1) * CDIM;
                const float w0 = (bx0 && by0) ? wx0 * wy0 : 0.f;
                const float w1 = (bx1 && by0) ? wx1 * wy0 : 0.f;
                const float w2 = (bx0 && by1) ? wx0 * wy1 : 0.f;
                const float w3 = (bx1 && by1) ? wx1 * wy1 : 0.f;
                s_w[p][t][0] = w0; s_w[p][t][1] = w1; s_w[p][t][2] = w2; s_w[p][t][3] = w3;
                pred = valid && ((w0 + w1 + w2 + w3) != 0.f);
            } else {
                s_off[p][18][0] = 0; s_off[p][18][1] = 0; s_off[p][18][2] = 0; s_off[p][18][3] = 0;
                s_w[p][18][0] = 0.f; s_w[p][18][1] = 0.f; s_w[p][18][2] = 0.f; s_w[p][18][3] = 0.f;
            }
            const unsigned long long mask = __ballot(pred);
            const int n = __popcll(mask);
            const int rank = __popcll(mask & ((1ull << t) - 1ull));
            if (pred) s_list[p][rank] = t;
            const int npad = (n + 7) & ~7;
            if (t < 8 && (n + t) < npad) s_list[p][n + t] = 18;
            if (t == 0) s_n[p] = npad;
        }
    }
    __syncthreads();

    // ---- per-point: bf16 partial sum + coalesced lvl1-3 gather ----
    #pragma unroll
    for (int p = 0; p < 2; ++p) {
        const int pt = pt0 + p;
        float acc = bf2f(accb[(0 * 1000 + pt) * CDIM + t]);
        acc += bf2f(accb[(1 * 1000 + pt) * CDIM + t]);
        acc += bf2f(accb[(2 * 1000 + pt) * CDIM + t]);
        acc += bf2f(accb[(3 * 1000 + pt) * CDIM + t]);
        acc += bf2f(accb[(4 * 1000 + pt) * CDIM + t]);
        acc += bf2f(accb[(5 * 1000 + pt) * CDIM + t]);

        const int npad = s_n[p];
        for (int base = 0; base < npad; base += 8) {
            float v[8][4];
            int tj[8];
            #pragma unroll
            for (int j = 0; j < 8; ++j) {
                const int tt = s_list[p][base + j];
                tj[j] = tt;
                v[j][0] = bf2f(wsb[s_off[p][tt][0] + t]);
                v[j][1] = bf2f(wsb[s_off[p][tt][1] + t]);
                v[j][2] = bf2f(wsb[s_off[p][tt][2] + t]);
                v[j][3] = bf2f(wsb[s_off[p][tt][3] + t]);
            }
            #pragma unroll
            for (int j = 0; j < 8; ++j) {
                const int tt = tj[j];
                acc += s_w[p][tt][0] * v[j][0] + s_w[p][tt][1] * v[j][1]
                     + s_w[p][tt][2] * v[j][2] + s_w[p][tt][3] * v[j][3];
            }
        }
        s_vec[p][t] = (acc * 0.25f) / 6.0f;
    }
    __syncthreads();

    // ---- hidden GEMV for 2 points: W1 loaded once, reused x2 ----
    const float* __restrict__ W1 = isDet ? W1d : W1m;
    const float bb = (isDet ? b1d : b1m)[t];
    float hs0 = bb, hs1 = bb;
    const float4* sv0 = (const float4*)s_vec[0];
    const float4* sv1 = (const float4*)s_vec[1];
    float wvA[32], wvB[32];
    #pragma unroll
    for (int i = 0; i < 32; ++i) wvA[i] = W1[i * CDIM + t];
    #pragma unroll
    for (int k0 = 0; k0 < CDIM; k0 += 64) {
        #pragma unroll
        for (int i = 0; i < 32; ++i) wvB[i] = W1[(k0 + 32 + i) * CDIM + t];
        #pragma unroll
        for (int i = 0; i < 8; ++i) {
            const float4 x0 = sv0[(k0 >> 2) + i];
            const float4 x1 = sv1[(k0 >> 2) + i];
            hs0 = fmaf(x0.x, wvA[4*i+0], hs0); hs1 = fmaf(x1.x, wvA[4*i+0], hs1);
            hs0 = fmaf(x0.y, wvA[4*i+1], hs0); hs1 = fmaf(x1.y, wvA[4*i+1], hs1);
            hs0 = fmaf(x0.z, wvA[4*i+2], hs0); hs1 = fmaf(x1.z, wvA[4*i+2], hs1);
            hs0 = fmaf(x0.w, wvA[4*i+3], hs0); hs1 = fmaf(x1.w, wvA[4*i+3], hs1);
        }
        if (k0 + 64 < CDIM) {
            #pragma unroll
            for (int i = 0; i < 32; ++i) wvA[i] = W1[(k0 + 64 + i) * CDIM + t];
        }
        #pragma unroll
        for (int i = 0; i < 8; ++i) {
            const float4 x0 = sv0[(k0 >> 2) + 8 + i];
            const float4 x1 = sv1[(k0 >> 2) + 8 + i];
            hs0 = fmaf(x0.x, wvB[4*i+0], hs0); hs1 = fmaf(x1.x, wvB[4*i+0], hs1);
            hs0 = fmaf(x0.y, wvB[4*i+1], hs0); hs1 = fmaf(x1.y, wvB[4*i+1], hs1);
            hs0 = fmaf(x0.z, wvB[4*i+2], hs0); hs1 = fmaf(x1.z, wvB[4*i+2], hs1);
            hs0 = fmaf(x0.w, wvB[4*i+3], hs0); hs1 = fmaf(x1.w, wvB[4*i+3], hs1);
        }
    }
    s_hid[0][t] = fmaxf(hs0, 0.f);
    s_hid[1][t] = fmaxf(hs1, 0.f);
    __syncthreads();

    // ---- heads: 16 lanes per output; weights loaded once, reused for 2 points ----
    const int g  = t >> 4;
    const int ln = t & 15;
    const int nOut = isDet ? 15 : 43;
    const int nrep = isDet ? 1 : 3;
    for (int rep = 0; rep < nrep; ++rep) {
        const int o = g + rep * 16;
        if (o < nOut) {
            const float* Wp; int stride, oo;
            if (isDet) {
                if (o < 4) { Wp = Wcd; stride = 4;  oo = o; }
                else       { Wp = Wod; stride = 11; oo = o - 4; }
            } else {
                if (o < 3) { Wp = Wcm; stride = 3;  oo = o; }
                else       { Wp = Wom; stride = 40; oo = o - 3; }
            }
            float wv[16];
            #pragma unroll
            for (int kk = 0; kk < 16; ++kk) wv[kk] = Wp[(ln + kk * 16) * stride + oo];
            #pragma unroll
            for (int p = 0; p < 2; ++p) {
                float sp = 0.f;
                #pragma unroll
                for (int kk = 0; kk < 16; ++kk) {
                    sp = fmaf(s_hid[p][ln + kk * 16], wv[kk], sp);
                }
                #pragma unroll
                for (int off = 1; off < 16; off <<= 1) sp += __shfl_xor(sp, off, 64);
                if (ln == 0) {
                    const int pt = pt0 + p;
                    const int m = pt - NDET;
                    float bias; int ooff;
                    if (isDet) {
                        if (o < 4) { bias = bcd[oo];                         ooff = pt * 4 + oo; }
                        else       { bias = bod[oo] + detfull[pt * 11 + oo]; ooff = 3600 + pt * 11 + oo; }
                    } else {
                        if (o < 3) { bias = bcm[oo];                         ooff = 13500 + m * 3 + oo; }
                        else       { bias = bom[oo] + mapanch[m * 40 + oo];  ooff = 13800 + m * 40 + oo; }
                    }
                    out[ooff] = sp + bias;
                }
            }
        }
    }
}

extern "C" void kernel_launch(void* const* d_in, const int* in_sizes, int n_in,
                              void* d_out, int out_size, void* d_ws, size_t ws_size,
                              hipStream_t stream) {
    const float* p2      = (const float*)d_in[0];
    const float* p3      = (const float*)d_in[1];
    const float* p4      = (const float*)d_in[2];
    const float* p5      = (const float*)d_in[3];
    const float* Kin     = (const float*)d_in[4];
    const float* Ein     = (const float*)d_in[5];
    const float* det3d   = (const float*)d_in[6];
    const float* detfull = (const float*)d_in[7];
    const float* mapanch = (const float*)d_in[8];
    const float* W1d     = (const float*)d_in[9];
    const float* b1d     = (const float*)d_in[10];
    const float* Wcd     = (const float*)d_in[11];
    const float* bcd     = (const float*)d_in[12];
    const float* Wod     = (const float*)d_in[13];
    const float* bod     = (const float*)d_in[14];
    const float* W1m     = (const float*)d_in[15];
    const float* b1m     = (const float*)d_in[16];
    const float* Wcm     = (const float*)d_in[17];
    const float* bcm     = (const float*)d_in[18];
    const float* Wom     = (const float*)d_in[19];
    const float* bom     = (const float*)d_in[20];
    float* out = (float*)d_out;
    u16* wsb  = (u16*)d_ws;           // packed bf16 features
    u16* accb = wsb + UEND;           // [6][1000][256] bf16 level-0 partials

    k1_pack_p2<<<8070, 256, 0, stream>>>(
        p2, p3, p4, p5, Kin, Ein, det3d, mapanch, wsb, accb);

    k2_gather_mlp<<<500, 256, 0, stream>>>(
        wsb, accb, Kin, Ein, det3d, detfull, mapanch,
        W1d, b1d, Wcd, bcd, Wod, bod, W1m, b1m, Wcm, bcm, Wom, bom, out);
}